// Round 4
// baseline (718.995 us; speedup 1.0000x reference)
//
#include <hip/hip_runtime.h>
#include <hip/hip_bf16.h>

#define NN 100000
#define NE 1200000
#define NG 512
#define NB ((NN + 127) / 128)   // dst buckets of 128 nodes

// ---------------- CSR build ----------------
__global__ void k_init_cnt(int* cnt, int n) {
    int i = blockIdx.x * blockDim.x + threadIdx.x;
    if (i < n) cnt[i] = 1;  // self-loop contributes 1 per node
}

__global__ void k_hist(const int* __restrict__ dst, int e, int* cnt) {
    int i = blockIdx.x * blockDim.x + threadIdx.x;
    if (i < e) atomicAdd(&cnt[dst[i]], 1);
}

__global__ void k_scan1(const int* __restrict__ cnt, int n, int* ex, int* blkSum) {
    __shared__ int s[1024];
    int i = blockIdx.x * 1024 + threadIdx.x;
    int v = (i < n) ? cnt[i] : 0;
    s[threadIdx.x] = v;
    __syncthreads();
    for (int off = 1; off < 1024; off <<= 1) {
        int t = (threadIdx.x >= off) ? s[threadIdx.x - off] : 0;
        __syncthreads();
        s[threadIdx.x] += t;
        __syncthreads();
    }
    if (i < n) ex[i] = s[threadIdx.x] - v;   // exclusive within block
    if (threadIdx.x == 1023) blkSum[blockIdx.x] = s[1023];
}

__global__ void k_scan2(const int* __restrict__ blkSum, int nb, int* blkOff, int* totalOut) {
    __shared__ int s[128];
    int t = threadIdx.x;
    int v = (t < nb) ? blkSum[t] : 0;
    s[t] = v;
    __syncthreads();
    for (int off = 1; off < 128; off <<= 1) {
        int x = (t >= off) ? s[t - off] : 0;
        __syncthreads();
        s[t] += x;
        __syncthreads();
    }
    if (t < nb) blkOff[t] = s[t] - v;
    if (t == 127) *totalOut = s[127];  // row_ptr[N] = total edge count
}

__global__ void k_scan3(int* row_ptr, int* cursor, const int* __restrict__ blkOff, int n) {
    int i = blockIdx.x * blockDim.x + threadIdx.x;
    if (i < n) {
        int v = row_ptr[i] + blkOff[i >> 10];
        row_ptr[i] = v;
        cursor[i] = v;
    }
}

// bucket cursors: bucket b of 128 dsts starts at row_ptr[b*128] minus the
// b*128 self-loops that precede it (self-loops are inserted in pass B).
__global__ void k_binit(const int* __restrict__ row_ptr, int* bcur) {
    int b = blockIdx.x * blockDim.x + threadIdx.x;
    if (b < NB) bcur[b] = row_ptr[b * 128] - b * 128;
}

// pass A: scatter (src,dst) records into per-bucket regions (dense writes)
__global__ void k_scatA(const int* __restrict__ srcA, const int* __restrict__ dstA,
                        int e, int* bcur, uint2* __restrict__ ebuf) {
    int i = blockIdx.x * blockDim.x + threadIdx.x;
    if (i < e) {
        int s = srcA[i], d = dstA[i];
        int pos = atomicAdd(&bcur[d >> 7], 1);
        ebuf[pos] = make_uint2((unsigned)s, (unsigned)d);
    }
}

// pass B: records are bucket-grouped -> col writes land in ~7KB windows
__global__ void k_scatB(const uint2* __restrict__ ebuf, int e, int n,
                        int* cursor, int* __restrict__ col) {
    int i = blockIdx.x * blockDim.x + threadIdx.x;
    if (i < e) {
        uint2 r = ebuf[i];
        int pos = atomicAdd(&cursor[(int)r.y], 1);
        col[pos] = (int)r.x;
    } else if (i < e + n) {
        int v = i - e;  // self loop
        int pos = atomicAdd(&cursor[v], 1);
        col[pos] = v;
    }
}

// ---------------- tiled GEMM + attention scores ----------------
// H = X @ W  (X:[n,K], W:[K,64]); ssrc = H.a_src, sdst = H.a_dst per row.
template <int K>
__global__ __launch_bounds__(256) void k_gemm_att(
    const float* __restrict__ X, const float* __restrict__ W,
    const float* __restrict__ a_src, const float* __restrict__ a_dst,
    float* __restrict__ H, float* __restrict__ ssrc, float* __restrict__ sdst, int n) {
    constexpr int KP = K + 8;              // padded X row stride (floats)
    __shared__ float Xs[64 * KP];
    __shared__ float Ws[K * 68];           // padded W row stride = 68
    const int tid = threadIdx.x;
    const int row0 = blockIdx.x * 64;

    for (int i = tid; i < K * 16; i += 256) {
        int k = i >> 4, c4 = i & 15;
        float4 v = reinterpret_cast<const float4*>(W)[i];
        *reinterpret_cast<float4*>(&Ws[k * 68 + c4 * 4]) = v;
    }
    constexpr int RQ = K / 4;              // float4s per row
    for (int i = tid; i < 64 * RQ; i += 256) {
        int r = i / RQ, c4 = i % RQ;
        float4 v = make_float4(0.f, 0.f, 0.f, 0.f);
        if (row0 + r < n) v = reinterpret_cast<const float4*>(X + (size_t)(row0 + r) * K)[c4];
        *reinterpret_cast<float4*>(&Xs[r * KP + c4 * 4]) = v;
    }
    __syncthreads();

    const int tx = tid & 15, ty = tid >> 4;   // 16x16 thread grid
    float acc[4][4] = {};
    for (int k = 0; k < K; k += 4) {
        float4 xv[4], wv[4];
#pragma unroll
        for (int r = 0; r < 4; ++r)
            xv[r] = *reinterpret_cast<const float4*>(&Xs[(ty * 4 + r) * KP + k]);
#pragma unroll
        for (int j = 0; j < 4; ++j)
            wv[j] = *reinterpret_cast<const float4*>(&Ws[(k + j) * 68 + tx * 4]);
#pragma unroll
        for (int r = 0; r < 4; ++r) {
            const float* xp = reinterpret_cast<const float*>(&xv[r]);
#pragma unroll
            for (int j = 0; j < 4; ++j) {
                const float* wp = reinterpret_cast<const float*>(&wv[j]);
#pragma unroll
                for (int c = 0; c < 4; ++c) acc[r][c] += xp[j] * wp[c];
            }
        }
    }

    float4 av = reinterpret_cast<const float4*>(a_src)[tx];
    float4 dv = reinterpret_cast<const float4*>(a_dst)[tx];
#pragma unroll
    for (int r = 0; r < 4; ++r) {
        int row = row0 + ty * 4 + r;
        if (row < n) {
            float4 o = make_float4(acc[r][0], acc[r][1], acc[r][2], acc[r][3]);
            reinterpret_cast<float4*>(H + (size_t)row * 64)[tx] = o;
            float ps = acc[r][0] * av.x + acc[r][1] * av.y + acc[r][2] * av.z + acc[r][3] * av.w;
            float pd = acc[r][0] * dv.x + acc[r][1] * dv.y + acc[r][2] * dv.z + acc[r][3] * dv.w;
#pragma unroll
            for (int off = 1; off < 16; off <<= 1) {
                ps += __shfl_xor(ps, off);
                pd += __shfl_xor(pd, off);
            }
            if (tx == 0) {
                ssrc[row] = ps;
                sdst[row] = pd;
            }
        }
    }
}

// ---------------- fused softmax + aggregation (wave per dst) ----------------
__global__ __launch_bounds__(256) void k_agg3(
    const float* __restrict__ H, const float* __restrict__ ssrc,
    const float* __restrict__ sdst, const int* __restrict__ row_ptr,
    const int* __restrict__ col, const float* __restrict__ bias,
    float* __restrict__ Y, int n) {
    int dst = blockIdx.x * 4 + (threadIdx.x >> 6);
    int lane = threadIdx.x & 63;
    if (dst >= n) return;
    int beg = row_ptr[dst], end = row_ptr[dst + 1];
    int deg = end - beg;
    float sd = sdst[dst];
    float acc = 0.f, den;

    if (deg <= 64) {
        // phase 1: lane = edge slot
        int s_l = (lane < deg) ? col[beg + lane] : 0;
        float e = -INFINITY;
        if (lane < deg) {
            e = ssrc[s_l] + sd;
            e = (e > 0.f) ? e : 0.2f * e;
        }
        float m = e;
#pragma unroll
        for (int off = 32; off; off >>= 1) m = fmaxf(m, __shfl_xor(m, off));
        float w_l = (lane < deg) ? __expf(e - m) : 0.f;
        float t = w_l;
#pragma unroll
        for (int off = 32; off; off >>= 1) t += __shfl_xor(t, off);
        den = t;
        // phase 2: lane = feature; broadcast (s,w) via shuffle
        int jj = 0;
        for (; jj + 4 <= deg; jj += 4) {
            int s0 = __shfl(s_l, jj), s1 = __shfl(s_l, jj + 1);
            int s2 = __shfl(s_l, jj + 2), s3 = __shfl(s_l, jj + 3);
            float w0 = __shfl(w_l, jj), w1 = __shfl(w_l, jj + 1);
            float w2 = __shfl(w_l, jj + 2), w3 = __shfl(w_l, jj + 3);
            float h0 = H[(size_t)s0 * 64 + lane];
            float h1 = H[(size_t)s1 * 64 + lane];
            float h2 = H[(size_t)s2 * 64 + lane];
            float h3 = H[(size_t)s3 * 64 + lane];
            acc += w0 * h0;
            acc += w1 * h1;
            acc += w2 * h2;
            acc += w3 * h3;
        }
        for (; jj < deg; ++jj)
            acc += __shfl(w_l, jj) * H[(size_t)__shfl(s_l, jj) * 64 + lane];
    } else {
        // slow path: online softmax over chunks of 64, then recompute w per edge
        float m = -INFINITY, d2 = 0.f;
        for (int c = beg; c < end; c += 64) {
            int j = c + lane;
            float e = -INFINITY;
            if (j < end) {
                e = ssrc[col[j]] + sd;
                e = (e > 0.f) ? e : 0.2f * e;
            }
            float cm = e;
#pragma unroll
            for (int off = 32; off; off >>= 1) cm = fmaxf(cm, __shfl_xor(cm, off));
            float nm = fmaxf(m, cm);
            float term = (j < end) ? __expf(e - nm) : 0.f;
#pragma unroll
            for (int off = 32; off; off >>= 1) term += __shfl_xor(term, off);
            d2 = d2 * __expf(m - nm) + term;
            m = nm;
        }
        den = d2;
        for (int j = beg; j < end; ++j) {
            int s = col[j];
            float e = ssrc[s] + sd;
            e = (e > 0.f) ? e : 0.2f * e;
            acc += __expf(e - m) * H[(size_t)s * 64 + lane];
        }
    }
    float o = acc / den + bias[lane];
    Y[(size_t)dst * 64 + lane] = fmaxf(o, 0.f);
}

// ---------------- pooling boundaries + pool + FC ----------------
__global__ void k_gstart(const int* __restrict__ batch, int n, int* gs) {
    int g = blockIdx.x * blockDim.x + threadIdx.x;
    if (g > NG) return;
    int lo = 0, hi = n;
    while (lo < hi) {
        int mid = (lo + hi) >> 1;
        if (batch[mid] < g) lo = mid + 1; else hi = mid;
    }
    gs[g] = lo;
}

__global__ __launch_bounds__(64) void k_pool_fc(
    const float* __restrict__ Y, const int* __restrict__ gs,
    const float* __restrict__ fcW, const float* __restrict__ fcb,
    float* __restrict__ out) {
    __shared__ float p[64];
    int g = blockIdx.x, lane = threadIdx.x;
    int b = gs[g], e = gs[g + 1];
    float s = 0.f;
    for (int r = b; r < e; ++r) s += Y[(size_t)r * 64 + lane];
    int cnt = e - b;
    p[lane] = s / (float)(cnt > 0 ? cnt : 1);
    __syncthreads();
    if (lane < 32) {
        float acc = fcb[lane];
#pragma unroll
        for (int k = 0; k < 64; ++k) acc += p[k] * fcW[k * 32 + lane];
        out[g * 32 + lane] = acc;
    }
}

// ---------------- launch ----------------
extern "C" void kernel_launch(void* const* d_in, const int* in_sizes, int n_in,
                              void* d_out, int out_size, void* d_ws, size_t ws_size,
                              hipStream_t stream) {
    const float* x = (const float*)d_in[0];
    const int* ei = (const int*)d_in[1];
    const int* batch = (const int*)d_in[2];
    const float* W0 = (const float*)d_in[3];
    const float* as0 = (const float*)d_in[4];
    const float* ad0 = (const float*)d_in[5];
    const float* b0 = (const float*)d_in[6];
    const float* W1 = (const float*)d_in[7];
    const float* as1 = (const float*)d_in[8];
    const float* ad1 = (const float*)d_in[9];
    const float* b1 = (const float*)d_in[10];
    const float* W2 = (const float*)d_in[11];
    const float* as2 = (const float*)d_in[12];
    const float* ad2 = (const float*)d_in[13];
    const float* b2 = (const float*)d_in[14];
    const float* fcW = (const float*)d_in[15];
    const float* fcb = (const float*)d_in[16];
    float* out = (float*)d_out;

    char* w = (char*)d_ws;
    auto alloc = [&](size_t bytes) {
        void* p = (void*)w;
        w += (bytes + 255) & ~(size_t)255;
        return p;
    };
    int* cnt_cursor = (int*)alloc((size_t)NN * 4);       // counts, then cursor
    int* row_ptr = (int*)alloc((size_t)(NN + 1) * 4);
    int* blkSum = (int*)alloc(512);
    int* blkOff = (int*)alloc(512);
    int* bcur = (int*)alloc((size_t)NB * 4);
    int* col = (int*)alloc((size_t)(NE + NN) * 4);
    int* gs = (int*)alloc((size_t)(NG + 1) * 4);
    uint2* ebuf = (uint2*)alloc((size_t)NE * 8);
    float* H = (float*)alloc((size_t)NN * 64 * 4);
    float* Y = (float*)alloc((size_t)NN * 64 * 4);
    float* ssrc = (float*)alloc((size_t)NN * 4);
    float* sdst = (float*)alloc((size_t)NN * 4);

    const int* srcA = ei;
    const int* dstA = ei + NE;

    // CSR build (bucketed two-phase scatter)
    k_init_cnt<<<(NN + 255) / 256, 256, 0, stream>>>(cnt_cursor, NN);
    k_hist<<<(NE + 255) / 256, 256, 0, stream>>>(dstA, NE, cnt_cursor);
    const int nb = (NN + 1023) / 1024;  // 98
    k_scan1<<<nb, 1024, 0, stream>>>(cnt_cursor, NN, row_ptr, blkSum);
    k_scan2<<<1, 128, 0, stream>>>(blkSum, nb, blkOff, row_ptr + NN);
    k_scan3<<<(NN + 255) / 256, 256, 0, stream>>>(row_ptr, cnt_cursor, blkOff, NN);
    k_binit<<<(NB + 255) / 256, 256, 0, stream>>>(row_ptr, bcur);
    k_scatA<<<(NE + 255) / 256, 256, 0, stream>>>(srcA, dstA, NE, bcur, ebuf);
    k_scatB<<<(NE + NN + 255) / 256, 256, 0, stream>>>(ebuf, NE, NN, cnt_cursor, col);
    k_gstart<<<3, 256, 0, stream>>>(batch, NN, gs);

    const int gemm_grid = (NN + 63) / 64;   // 64-row tile per block
    const int agg_grid = (NN + 3) / 4;      // 4 waves per block, wave per dst

    // layer 0
    k_gemm_att<128><<<gemm_grid, 256, 0, stream>>>(x, W0, as0, ad0, H, ssrc, sdst, NN);
    k_agg3<<<agg_grid, 256, 0, stream>>>(H, ssrc, sdst, row_ptr, col, b0, Y, NN);
    // layer 1
    k_gemm_att<64><<<gemm_grid, 256, 0, stream>>>(Y, W1, as1, ad1, H, ssrc, sdst, NN);
    k_agg3<<<agg_grid, 256, 0, stream>>>(H, ssrc, sdst, row_ptr, col, b1, Y, NN);
    // layer 2
    k_gemm_att<64><<<gemm_grid, 256, 0, stream>>>(Y, W2, as2, ad2, H, ssrc, sdst, NN);
    k_agg3<<<agg_grid, 256, 0, stream>>>(H, ssrc, sdst, row_ptr, col, b2, Y, NN);

    // pool + FC
    k_pool_fc<<<NG, 64, 0, stream>>>(Y, gs, fcW, fcb, out);
}

// Round 5
// 494.178 us; speedup vs baseline: 1.4549x; 1.4549x over previous
//
#include <hip/hip_runtime.h>
#include <hip/hip_bf16.h>

#define NN 100000
#define NE 1200000
#define NG 512

// ---------------- CSR build ----------------
__global__ void k_init_cnt(int* cnt, int n) {
    int i = blockIdx.x * blockDim.x + threadIdx.x;
    if (i < n) cnt[i] = 1;  // self-loop contributes 1 per node
}

__global__ void k_hist(const int* __restrict__ dst, int e, int* cnt) {
    int i = blockIdx.x * blockDim.x + threadIdx.x;
    if (i < e) atomicAdd(&cnt[dst[i]], 1);
}

__global__ void k_scan1(const int* __restrict__ cnt, int n, int* ex, int* blkSum) {
    __shared__ int s[1024];
    int i = blockIdx.x * 1024 + threadIdx.x;
    int v = (i < n) ? cnt[i] : 0;
    s[threadIdx.x] = v;
    __syncthreads();
    for (int off = 1; off < 1024; off <<= 1) {
        int t = (threadIdx.x >= off) ? s[threadIdx.x - off] : 0;
        __syncthreads();
        s[threadIdx.x] += t;
        __syncthreads();
    }
    if (i < n) ex[i] = s[threadIdx.x] - v;   // exclusive within block
    if (threadIdx.x == 1023) blkSum[blockIdx.x] = s[1023];
}

__global__ void k_scan2(const int* __restrict__ blkSum, int nb, int* blkOff, int* totalOut) {
    __shared__ int s[128];
    int t = threadIdx.x;
    int v = (t < nb) ? blkSum[t] : 0;
    s[t] = v;
    __syncthreads();
    for (int off = 1; off < 128; off <<= 1) {
        int x = (t >= off) ? s[t - off] : 0;
        __syncthreads();
        s[t] += x;
        __syncthreads();
    }
    if (t < nb) blkOff[t] = s[t] - v;
    if (t == 127) *totalOut = s[127];  // row_ptr[N] = total edge count
}

__global__ void k_scan3(int* row_ptr, int* cursor, const int* __restrict__ blkOff, int n) {
    int i = blockIdx.x * blockDim.x + threadIdx.x;
    if (i < n) {
        int v = row_ptr[i] + blkOff[i >> 10];
        row_ptr[i] = v;
        cursor[i] = v;
    }
}

__global__ void k_scatter(const int* __restrict__ srcA, const int* __restrict__ dstA,
                          int e, int n, int* cursor, int* __restrict__ col) {
    int i = blockIdx.x * blockDim.x + threadIdx.x;
    if (i < e) {
        int d = dstA[i];
        int pos = atomicAdd(&cursor[d], 1);
        col[pos] = srcA[i];
    } else if (i < e + n) {
        int v = i - e;  // self loop
        int pos = atomicAdd(&cursor[v], 1);
        col[pos] = v;
    }
}

// ---------------- tiled GEMM + attention scores ----------------
// H = X @ W  (X:[n,K], W:[K,64]); ssrc = H.a_src, sdst = H.a_dst per row.
template <int K>
__global__ __launch_bounds__(256) void k_gemm_att(
    const float* __restrict__ X, const float* __restrict__ W,
    const float* __restrict__ a_src, const float* __restrict__ a_dst,
    float* __restrict__ H, float* __restrict__ ssrc, float* __restrict__ sdst, int n) {
    constexpr int KP = K + 8;              // padded X row stride (floats)
    __shared__ float Xs[64 * KP];
    __shared__ float Ws[K * 68];           // padded W row stride = 68
    const int tid = threadIdx.x;
    const int row0 = blockIdx.x * 64;

    for (int i = tid; i < K * 16; i += 256) {
        int k = i >> 4, c4 = i & 15;
        float4 v = reinterpret_cast<const float4*>(W)[i];
        *reinterpret_cast<float4*>(&Ws[k * 68 + c4 * 4]) = v;
    }
    constexpr int RQ = K / 4;              // float4s per row
    for (int i = tid; i < 64 * RQ; i += 256) {
        int r = i / RQ, c4 = i % RQ;
        float4 v = make_float4(0.f, 0.f, 0.f, 0.f);
        if (row0 + r < n) v = reinterpret_cast<const float4*>(X + (size_t)(row0 + r) * K)[c4];
        *reinterpret_cast<float4*>(&Xs[r * KP + c4 * 4]) = v;
    }
    __syncthreads();

    const int tx = tid & 15, ty = tid >> 4;   // 16x16 thread grid
    float acc[4][4] = {};
    for (int k = 0; k < K; k += 4) {
        float4 xv[4], wv[4];
#pragma unroll
        for (int r = 0; r < 4; ++r)
            xv[r] = *reinterpret_cast<const float4*>(&Xs[(ty * 4 + r) * KP + k]);
#pragma unroll
        for (int j = 0; j < 4; ++j)
            wv[j] = *reinterpret_cast<const float4*>(&Ws[(k + j) * 68 + tx * 4]);
#pragma unroll
        for (int r = 0; r < 4; ++r) {
            const float* xp = reinterpret_cast<const float*>(&xv[r]);
#pragma unroll
            for (int j = 0; j < 4; ++j) {
                const float* wp = reinterpret_cast<const float*>(&wv[j]);
#pragma unroll
                for (int c = 0; c < 4; ++c) acc[r][c] += xp[j] * wp[c];
            }
        }
    }

    float4 av = reinterpret_cast<const float4*>(a_src)[tx];
    float4 dv = reinterpret_cast<const float4*>(a_dst)[tx];
#pragma unroll
    for (int r = 0; r < 4; ++r) {
        int row = row0 + ty * 4 + r;
        if (row < n) {
            float4 o = make_float4(acc[r][0], acc[r][1], acc[r][2], acc[r][3]);
            reinterpret_cast<float4*>(H + (size_t)row * 64)[tx] = o;
            float ps = acc[r][0] * av.x + acc[r][1] * av.y + acc[r][2] * av.z + acc[r][3] * av.w;
            float pd = acc[r][0] * dv.x + acc[r][1] * dv.y + acc[r][2] * dv.z + acc[r][3] * dv.w;
#pragma unroll
            for (int off = 1; off < 16; off <<= 1) {
                ps += __shfl_xor(ps, off);
                pd += __shfl_xor(pd, off);
            }
            if (tx == 0) {
                ssrc[row] = ps;
                sdst[row] = pd;
            }
        }
    }
}

// ---------------- fused softmax + aggregation (wave per dst) ----------------
// phase 1: lane = edge slot (softmax). phase 2: 4 groups x 16 lanes, each
// group gathers one full H row as 16 x float4 -> 4 rows per wave-issue.
__global__ __launch_bounds__(256) void k_agg4(
    const float4* __restrict__ H4, const float* __restrict__ ssrc,
    const float* __restrict__ sdst, const int* __restrict__ row_ptr,
    const int* __restrict__ col, const float4* __restrict__ bias4,
    float4* __restrict__ Y4, int n) {
    int dst = blockIdx.x * 4 + (threadIdx.x >> 6);
    int lane = threadIdx.x & 63;
    if (dst >= n) return;
    int beg = row_ptr[dst], end = row_ptr[dst + 1];
    int deg = end - beg;
    float sd = sdst[dst];
    const int grp = lane >> 4;   // edge group 0..3
    const int fl = lane & 15;    // float4 index within row
    float4 acc = make_float4(0.f, 0.f, 0.f, 0.f);
    float den;

    if (deg <= 64) {
        // phase 1: lane = edge slot
        int s_l = 0;
        float e = -INFINITY;
        if (lane < deg) {
            s_l = col[beg + lane];
            e = ssrc[s_l] + sd;
            e = (e > 0.f) ? e : 0.2f * e;
        }
        float m = e;
#pragma unroll
        for (int off = 32; off; off >>= 1) m = fmaxf(m, __shfl_xor(m, off));
        float w_l = (lane < deg) ? __expf(e - m) : 0.f;
        den = w_l;
#pragma unroll
        for (int off = 32; off; off >>= 1) den += __shfl_xor(den, off);

        // phase 2: 8 edges per iteration (2 per group, 2 loads in flight)
        for (int jj = 0; jj < deg; jj += 8) {
            int j0 = jj + grp, j1 = jj + 4 + grp;
            int s0 = __shfl(s_l, j0), s1 = __shfl(s_l, j1);
            float w0 = __shfl(w_l, j0), w1 = __shfl(w_l, j1);
            if (j0 < deg) {
                float4 h = H4[(size_t)s0 * 16 + fl];
                acc.x += w0 * h.x; acc.y += w0 * h.y;
                acc.z += w0 * h.z; acc.w += w0 * h.w;
            }
            if (j1 < deg) {
                float4 h = H4[(size_t)s1 * 16 + fl];
                acc.x += w1 * h.x; acc.y += w1 * h.y;
                acc.z += w1 * h.z; acc.w += w1 * h.w;
            }
        }
    } else {
        // slow path: online softmax over chunks of 64, then grouped accumulate
        float m = -INFINITY, d2 = 0.f;
        for (int c = beg; c < end; c += 64) {
            int j = c + lane;
            float e = -INFINITY;
            if (j < end) {
                e = ssrc[col[j]] + sd;
                e = (e > 0.f) ? e : 0.2f * e;
            }
            float cm = e;
#pragma unroll
            for (int off = 32; off; off >>= 1) cm = fmaxf(cm, __shfl_xor(cm, off));
            float nm = fmaxf(m, cm);
            float term = (j < end) ? __expf(e - nm) : 0.f;
#pragma unroll
            for (int off = 32; off; off >>= 1) term += __shfl_xor(term, off);
            d2 = d2 * __expf(m - nm) + term;
            m = nm;
        }
        den = d2;
        for (int jj = 0; jj < deg; jj += 8) {
            int j0 = beg + jj + grp, j1 = beg + jj + 4 + grp;
            if (j0 < end) {
                int s = col[j0];
                float e = ssrc[s] + sd;
                e = (e > 0.f) ? e : 0.2f * e;
                float w = __expf(e - m);
                float4 h = H4[(size_t)s * 16 + fl];
                acc.x += w * h.x; acc.y += w * h.y;
                acc.z += w * h.z; acc.w += w * h.w;
            }
            if (j1 < end) {
                int s = col[j1];
                float e = ssrc[s] + sd;
                e = (e > 0.f) ? e : 0.2f * e;
                float w = __expf(e - m);
                float4 h = H4[(size_t)s * 16 + fl];
                acc.x += w * h.x; acc.y += w * h.y;
                acc.z += w * h.z; acc.w += w * h.w;
            }
        }
    }

    // cross-group reduce: sum the 4 edge-group partials (same fl)
#pragma unroll
    for (int off = 16; off < 64; off <<= 1) {
        acc.x += __shfl_xor(acc.x, off);
        acc.y += __shfl_xor(acc.y, off);
        acc.z += __shfl_xor(acc.z, off);
        acc.w += __shfl_xor(acc.w, off);
    }
    if (grp == 0) {
        float inv = 1.f / den;
        float4 b = bias4[fl];
        float4 o;
        o.x = fmaxf(acc.x * inv + b.x, 0.f);
        o.y = fmaxf(acc.y * inv + b.y, 0.f);
        o.z = fmaxf(acc.z * inv + b.z, 0.f);
        o.w = fmaxf(acc.w * inv + b.w, 0.f);
        Y4[(size_t)dst * 16 + fl] = o;
    }
}

// ---------------- pooling boundaries + pool + FC ----------------
__global__ void k_gstart(const int* __restrict__ batch, int n, int* gs) {
    int g = blockIdx.x * blockDim.x + threadIdx.x;
    if (g > NG) return;
    int lo = 0, hi = n;
    while (lo < hi) {
        int mid = (lo + hi) >> 1;
        if (batch[mid] < g) lo = mid + 1; else hi = mid;
    }
    gs[g] = lo;
}

__global__ __launch_bounds__(64) void k_pool_fc(
    const float* __restrict__ Y, const int* __restrict__ gs,
    const float* __restrict__ fcW, const float* __restrict__ fcb,
    float* __restrict__ out) {
    __shared__ float p[64];
    int g = blockIdx.x, lane = threadIdx.x;
    int b = gs[g], e = gs[g + 1];
    float s = 0.f;
    for (int r = b; r < e; ++r) s += Y[(size_t)r * 64 + lane];
    int cnt = e - b;
    p[lane] = s / (float)(cnt > 0 ? cnt : 1);
    __syncthreads();
    if (lane < 32) {
        float acc = fcb[lane];
#pragma unroll
        for (int k = 0; k < 64; ++k) acc += p[k] * fcW[k * 32 + lane];
        out[g * 32 + lane] = acc;
    }
}

// ---------------- launch ----------------
extern "C" void kernel_launch(void* const* d_in, const int* in_sizes, int n_in,
                              void* d_out, int out_size, void* d_ws, size_t ws_size,
                              hipStream_t stream) {
    const float* x = (const float*)d_in[0];
    const int* ei = (const int*)d_in[1];
    const int* batch = (const int*)d_in[2];
    const float* W0 = (const float*)d_in[3];
    const float* as0 = (const float*)d_in[4];
    const float* ad0 = (const float*)d_in[5];
    const float* b0 = (const float*)d_in[6];
    const float* W1 = (const float*)d_in[7];
    const float* as1 = (const float*)d_in[8];
    const float* ad1 = (const float*)d_in[9];
    const float* b1 = (const float*)d_in[10];
    const float* W2 = (const float*)d_in[11];
    const float* as2 = (const float*)d_in[12];
    const float* ad2 = (const float*)d_in[13];
    const float* b2 = (const float*)d_in[14];
    const float* fcW = (const float*)d_in[15];
    const float* fcb = (const float*)d_in[16];
    float* out = (float*)d_out;

    char* w = (char*)d_ws;
    auto alloc = [&](size_t bytes) {
        void* p = (void*)w;
        w += (bytes + 255) & ~(size_t)255;
        return p;
    };
    int* cnt_cursor = (int*)alloc((size_t)NN * 4);       // counts, then cursor
    int* row_ptr = (int*)alloc((size_t)(NN + 1) * 4);
    int* blkSum = (int*)alloc(512);
    int* blkOff = (int*)alloc(512);
    int* col = (int*)alloc((size_t)(NE + NN) * 4);
    int* gs = (int*)alloc((size_t)(NG + 1) * 4);
    float* H = (float*)alloc((size_t)NN * 64 * 4);
    float* Y = (float*)alloc((size_t)NN * 64 * 4);
    float* ssrc = (float*)alloc((size_t)NN * 4);
    float* sdst = (float*)alloc((size_t)NN * 4);

    const int* srcA = ei;
    const int* dstA = ei + NE;

    // CSR build (direct scatter — proven fastest variant)
    k_init_cnt<<<(NN + 255) / 256, 256, 0, stream>>>(cnt_cursor, NN);
    k_hist<<<(NE + 255) / 256, 256, 0, stream>>>(dstA, NE, cnt_cursor);
    const int nb = (NN + 1023) / 1024;  // 98
    k_scan1<<<nb, 1024, 0, stream>>>(cnt_cursor, NN, row_ptr, blkSum);
    k_scan2<<<1, 128, 0, stream>>>(blkSum, nb, blkOff, row_ptr + NN);
    k_scan3<<<(NN + 255) / 256, 256, 0, stream>>>(row_ptr, cnt_cursor, blkOff, NN);
    k_scatter<<<(NE + NN + 255) / 256, 256, 0, stream>>>(srcA, dstA, NE, NN, cnt_cursor, col);
    k_gstart<<<3, 256, 0, stream>>>(batch, NN, gs);

    const int gemm_grid = (NN + 63) / 64;   // 64-row tile per block
    const int agg_grid = (NN + 3) / 4;      // 4 waves per block, wave per dst

    // layer 0
    k_gemm_att<128><<<gemm_grid, 256, 0, stream>>>(x, W0, as0, ad0, H, ssrc, sdst, NN);
    k_agg4<<<agg_grid, 256, 0, stream>>>((const float4*)H, ssrc, sdst, row_ptr, col,
                                         (const float4*)b0, (float4*)Y, NN);
    // layer 1
    k_gemm_att<64><<<gemm_grid, 256, 0, stream>>>(Y, W1, as1, ad1, H, ssrc, sdst, NN);
    k_agg4<<<agg_grid, 256, 0, stream>>>((const float4*)H, ssrc, sdst, row_ptr, col,
                                         (const float4*)b1, (float4*)Y, NN);
    // layer 2
    k_gemm_att<64><<<gemm_grid, 256, 0, stream>>>(Y, W2, as2, ad2, H, ssrc, sdst, NN);
    k_agg4<<<agg_grid, 256, 0, stream>>>((const float4*)H, ssrc, sdst, row_ptr, col,
                                         (const float4*)b2, (float4*)Y, NN);

    // pool + FC
    k_pool_fc<<<NG, 64, 0, stream>>>(Y, gs, fcW, fcb, out);
}

// Round 6
// 426.461 us; speedup vs baseline: 1.6860x; 1.1588x over previous
//
#include <hip/hip_runtime.h>
#include <hip/hip_bf16.h>
#include <hip/hip_fp16.h>

#define NN 100000
#define NE 1200000
#define NG 512
#define NBK ((NN + 511) / 512)     // 196 dst buckets of 512 nodes
#define SBATCH 4096                 // edges per sort block
#define EPB (SBATCH / 256)          // edges per thread

// ---------------- CSR build ----------------
__global__ void k_init_cnt(int* cnt, int n) {
    int i = blockIdx.x * blockDim.x + threadIdx.x;
    if (i < n) cnt[i] = 1;  // self-loop contributes 1 per node
}

__global__ void k_hist(const int* __restrict__ dst, int e, int* cnt) {
    int i = blockIdx.x * blockDim.x + threadIdx.x;
    if (i < e) atomicAdd(&cnt[dst[i]], 1);
}

__global__ void k_scan1(const int* __restrict__ cnt, int n, int* ex, int* blkSum) {
    __shared__ int s[1024];
    int i = blockIdx.x * 1024 + threadIdx.x;
    int v = (i < n) ? cnt[i] : 0;
    s[threadIdx.x] = v;
    __syncthreads();
    for (int off = 1; off < 1024; off <<= 1) {
        int t = (threadIdx.x >= off) ? s[threadIdx.x - off] : 0;
        __syncthreads();
        s[threadIdx.x] += t;
        __syncthreads();
    }
    if (i < n) ex[i] = s[threadIdx.x] - v;   // exclusive within block
    if (threadIdx.x == 1023) blkSum[blockIdx.x] = s[1023];
}

__global__ void k_scan2(const int* __restrict__ blkSum, int nb, int* blkOff, int* totalOut) {
    __shared__ int s[128];
    int t = threadIdx.x;
    int v = (t < nb) ? blkSum[t] : 0;
    s[t] = v;
    __syncthreads();
    for (int off = 1; off < 128; off <<= 1) {
        int x = (t >= off) ? s[t - off] : 0;
        __syncthreads();
        s[t] += x;
        __syncthreads();
    }
    if (t < nb) blkOff[t] = s[t] - v;
    if (t == 127) *totalOut = s[127];  // row_ptr[N] = total edge count
}

__global__ void k_scan3(int* row_ptr, int* cursor, const int* __restrict__ blkOff, int n) {
    int i = blockIdx.x * blockDim.x + threadIdx.x;
    if (i < n) {
        int v = row_ptr[i] + blkOff[i >> 10];
        row_ptr[i] = v;
        cursor[i] = v;
    }
}

// bucket region start in ebuf: edges of dsts < b*512, excluding their self-loops
__global__ void k_binit(const int* __restrict__ row_ptr, int* gcur) {
    int b = blockIdx.x * blockDim.x + threadIdx.x;
    if (b < NBK) {
        int d0 = b * 512;
        if (d0 > NN) d0 = NN;
        gcur[b] = row_ptr[d0] - d0;
    }
}

// pass A: per-block LDS histogram + chunk reservation + dense record write
__global__ __launch_bounds__(256) void k_sortA(
    const int* __restrict__ srcA, const int* __restrict__ dstA, int e,
    int* gcur, uint2* __restrict__ ebuf) {
    __shared__ int cnt[NBK];
    __shared__ int base[NBK];
    const int t = threadIdx.x;
    const int i0 = blockIdx.x * SBATCH;
    for (int b = t; b < NBK; b += 256) cnt[b] = 0;
    __syncthreads();
#pragma unroll
    for (int k = 0; k < EPB; ++k) {
        int i = i0 + k * 256 + t;
        if (i < e) atomicAdd(&cnt[dstA[i] >> 9], 1);
    }
    __syncthreads();
    for (int b = t; b < NBK; b += 256) {
        int c = cnt[b];
        base[b] = c ? atomicAdd(&gcur[b], c) : 0;
        cnt[b] = 0;
    }
    __syncthreads();
#pragma unroll
    for (int k = 0; k < EPB; ++k) {
        int i = i0 + k * 256 + t;
        if (i < e) {
            int d = dstA[i], s = srcA[i];
            int b = d >> 9;
            int off = atomicAdd(&cnt[b], 1);
            ebuf[base[b] + off] = make_uint2((unsigned)s, (unsigned)d);
        }
    }
}

// pass B: bucket-grouped records -> col writes land in ~26KB windows
__global__ void k_sortB(const uint2* __restrict__ ebuf, int e, int n,
                        int* cursor, int* __restrict__ col) {
    int i = blockIdx.x * blockDim.x + threadIdx.x;
    if (i < e) {
        uint2 r = ebuf[i];
        int pos = atomicAdd(&cursor[(int)r.y], 1);
        col[pos] = (int)r.x;
    } else if (i < e + n) {
        int v = i - e;  // self loop
        int pos = atomicAdd(&cursor[v], 1);
        col[pos] = v;
    }
}

// ---------------- tiled GEMM + attention scores ----------------
// H(fp16) = X @ W  (X:[n,K] f32, W:[K,64]); ssrc = H.a_src, sdst = H.a_dst (f32).
template <int K>
__global__ __launch_bounds__(256) void k_gemm_att(
    const float* __restrict__ X, const float* __restrict__ W,
    const float* __restrict__ a_src, const float* __restrict__ a_dst,
    __half* __restrict__ H, float* __restrict__ ssrc, float* __restrict__ sdst, int n) {
    constexpr int KP = K + 8;              // padded X row stride (floats)
    __shared__ float Xs[64 * KP];
    __shared__ float Ws[K * 68];           // padded W row stride = 68
    const int tid = threadIdx.x;
    const int row0 = blockIdx.x * 64;

    for (int i = tid; i < K * 16; i += 256) {
        int k = i >> 4, c4 = i & 15;
        float4 v = reinterpret_cast<const float4*>(W)[i];
        *reinterpret_cast<float4*>(&Ws[k * 68 + c4 * 4]) = v;
    }
    constexpr int RQ = K / 4;              // float4s per row
    for (int i = tid; i < 64 * RQ; i += 256) {
        int r = i / RQ, c4 = i % RQ;
        float4 v = make_float4(0.f, 0.f, 0.f, 0.f);
        if (row0 + r < n) v = reinterpret_cast<const float4*>(X + (size_t)(row0 + r) * K)[c4];
        *reinterpret_cast<float4*>(&Xs[r * KP + c4 * 4]) = v;
    }
    __syncthreads();

    const int tx = tid & 15, ty = tid >> 4;   // 16x16 thread grid
    float acc[4][4] = {};
    for (int k = 0; k < K; k += 4) {
        float4 xv[4], wv[4];
#pragma unroll
        for (int r = 0; r < 4; ++r)
            xv[r] = *reinterpret_cast<const float4*>(&Xs[(ty * 4 + r) * KP + k]);
#pragma unroll
        for (int j = 0; j < 4; ++j)
            wv[j] = *reinterpret_cast<const float4*>(&Ws[(k + j) * 68 + tx * 4]);
#pragma unroll
        for (int r = 0; r < 4; ++r) {
            const float* xp = reinterpret_cast<const float*>(&xv[r]);
#pragma unroll
            for (int j = 0; j < 4; ++j) {
                const float* wp = reinterpret_cast<const float*>(&wv[j]);
#pragma unroll
                for (int c = 0; c < 4; ++c) acc[r][c] += xp[j] * wp[c];
            }
        }
    }

    float4 av = reinterpret_cast<const float4*>(a_src)[tx];
    float4 dv = reinterpret_cast<const float4*>(a_dst)[tx];
#pragma unroll
    for (int r = 0; r < 4; ++r) {
        int row = row0 + ty * 4 + r;
        if (row < n) {
            __half2 h01 = __floats2half2_rn(acc[r][0], acc[r][1]);
            __half2 h23 = __floats2half2_rn(acc[r][2], acc[r][3]);
            float2 packed;
            *reinterpret_cast<__half2*>(&packed.x) = h01;
            *reinterpret_cast<__half2*>(&packed.y) = h23;
            reinterpret_cast<float2*>(H + (size_t)row * 64)[tx] = packed;
            float ps = acc[r][0] * av.x + acc[r][1] * av.y + acc[r][2] * av.z + acc[r][3] * av.w;
            float pd = acc[r][0] * dv.x + acc[r][1] * dv.y + acc[r][2] * dv.z + acc[r][3] * dv.w;
#pragma unroll
            for (int off = 1; off < 16; off <<= 1) {
                ps += __shfl_xor(ps, off);
                pd += __shfl_xor(pd, off);
            }
            if (tx == 0) {
                ssrc[row] = ps;
                sdst[row] = pd;
            }
        }
    }
}

// ---------------- fused softmax + aggregation (wave per dst) ----------------
// phase 1: lane = edge slot (softmax). phase 2: 4 groups x 16 lanes; each
// group gathers one fp16 H row (16 x 8B) -> 4 rows per wave-issue.
__global__ __launch_bounds__(256) void k_agg4(
    const float2* __restrict__ H2, const float* __restrict__ ssrc,
    const float* __restrict__ sdst, const int* __restrict__ row_ptr,
    const int* __restrict__ col, const float4* __restrict__ bias4,
    float4* __restrict__ Y4, int n) {
    int dst = blockIdx.x * 4 + (threadIdx.x >> 6);
    int lane = threadIdx.x & 63;
    if (dst >= n) return;
    int beg = row_ptr[dst], end = row_ptr[dst + 1];
    int deg = end - beg;
    float sd = sdst[dst];
    const int grp = lane >> 4;   // edge group 0..3
    const int fl = lane & 15;    // 4-feature slot within row
    float4 acc = make_float4(0.f, 0.f, 0.f, 0.f);
    float den;

    auto fma_row = [&](int s, float w) {
        float2 raw = H2[(size_t)s * 16 + fl];
        const __half2* ph = reinterpret_cast<const __half2*>(&raw);
        float2 lo = __half22float2(ph[0]);
        float2 hi = __half22float2(ph[1]);
        acc.x += w * lo.x; acc.y += w * lo.y;
        acc.z += w * hi.x; acc.w += w * hi.y;
    };

    if (deg <= 64) {
        // phase 1: lane = edge slot
        int s_l = 0;
        float e = -INFINITY;
        if (lane < deg) {
            s_l = col[beg + lane];
            e = ssrc[s_l] + sd;
            e = (e > 0.f) ? e : 0.2f * e;
        }
        float m = e;
#pragma unroll
        for (int off = 32; off; off >>= 1) m = fmaxf(m, __shfl_xor(m, off));
        float w_l = (lane < deg) ? __expf(e - m) : 0.f;
        den = w_l;
#pragma unroll
        for (int off = 32; off; off >>= 1) den += __shfl_xor(den, off);

        // phase 2: 8 edges per iteration (2 per group)
        for (int jj = 0; jj < deg; jj += 8) {
            int j0 = jj + grp, j1 = jj + 4 + grp;
            int s0 = __shfl(s_l, j0), s1 = __shfl(s_l, j1);
            float w0 = __shfl(w_l, j0), w1 = __shfl(w_l, j1);
            if (j0 < deg) fma_row(s0, w0);
            if (j1 < deg) fma_row(s1, w1);
        }
    } else {
        // slow path: online softmax over chunks of 64, then grouped accumulate
        float m = -INFINITY, d2 = 0.f;
        for (int c = beg; c < end; c += 64) {
            int j = c + lane;
            float e = -INFINITY;
            if (j < end) {
                e = ssrc[col[j]] + sd;
                e = (e > 0.f) ? e : 0.2f * e;
            }
            float cm = e;
#pragma unroll
            for (int off = 32; off; off >>= 1) cm = fmaxf(cm, __shfl_xor(cm, off));
            float nm = fmaxf(m, cm);
            float term = (j < end) ? __expf(e - nm) : 0.f;
#pragma unroll
            for (int off = 32; off; off >>= 1) term += __shfl_xor(term, off);
            d2 = d2 * __expf(m - nm) + term;
            m = nm;
        }
        den = d2;
        for (int jj = 0; jj < deg; jj += 8) {
            int j0 = beg + jj + grp, j1 = beg + jj + 4 + grp;
            if (j0 < end) {
                int s = col[j0];
                float e = ssrc[s] + sd;
                e = (e > 0.f) ? e : 0.2f * e;
                fma_row(s, __expf(e - m));
            }
            if (j1 < end) {
                int s = col[j1];
                float e = ssrc[s] + sd;
                e = (e > 0.f) ? e : 0.2f * e;
                fma_row(s, __expf(e - m));
            }
        }
    }

    // cross-group reduce: sum the 4 edge-group partials (same fl)
#pragma unroll
    for (int off = 16; off < 64; off <<= 1) {
        acc.x += __shfl_xor(acc.x, off);
        acc.y += __shfl_xor(acc.y, off);
        acc.z += __shfl_xor(acc.z, off);
        acc.w += __shfl_xor(acc.w, off);
    }
    if (grp == 0) {
        float inv = 1.f / den;
        float4 b = bias4[fl];
        float4 o;
        o.x = fmaxf(acc.x * inv + b.x, 0.f);
        o.y = fmaxf(acc.y * inv + b.y, 0.f);
        o.z = fmaxf(acc.z * inv + b.z, 0.f);
        o.w = fmaxf(acc.w * inv + b.w, 0.f);
        Y4[(size_t)dst * 16 + fl] = o;
    }
}

// ---------------- pooling boundaries + pool + FC ----------------
__global__ void k_gstart(const int* __restrict__ batch, int n, int* gs) {
    int g = blockIdx.x * blockDim.x + threadIdx.x;
    if (g > NG) return;
    int lo = 0, hi = n;
    while (lo < hi) {
        int mid = (lo + hi) >> 1;
        if (batch[mid] < g) lo = mid + 1; else hi = mid;
    }
    gs[g] = lo;
}

__global__ __launch_bounds__(64) void k_pool_fc(
    const float* __restrict__ Y, const int* __restrict__ gs,
    const float* __restrict__ fcW, const float* __restrict__ fcb,
    float* __restrict__ out) {
    __shared__ float p[64];
    int g = blockIdx.x, lane = threadIdx.x;
    int b = gs[g], e = gs[g + 1];
    float s = 0.f;
    for (int r = b; r < e; ++r) s += Y[(size_t)r * 64 + lane];
    int cnt = e - b;
    p[lane] = s / (float)(cnt > 0 ? cnt : 1);
    __syncthreads();
    if (lane < 32) {
        float acc = fcb[lane];
#pragma unroll
        for (int k = 0; k < 64; ++k) acc += p[k] * fcW[k * 32 + lane];
        out[g * 32 + lane] = acc;
    }
}

// ---------------- launch ----------------
extern "C" void kernel_launch(void* const* d_in, const int* in_sizes, int n_in,
                              void* d_out, int out_size, void* d_ws, size_t ws_size,
                              hipStream_t stream) {
    const float* x = (const float*)d_in[0];
    const int* ei = (const int*)d_in[1];
    const int* batch = (const int*)d_in[2];
    const float* W0 = (const float*)d_in[3];
    const float* as0 = (const float*)d_in[4];
    const float* ad0 = (const float*)d_in[5];
    const float* b0 = (const float*)d_in[6];
    const float* W1 = (const float*)d_in[7];
    const float* as1 = (const float*)d_in[8];
    const float* ad1 = (const float*)d_in[9];
    const float* b1 = (const float*)d_in[10];
    const float* W2 = (const float*)d_in[11];
    const float* as2 = (const float*)d_in[12];
    const float* ad2 = (const float*)d_in[13];
    const float* b2 = (const float*)d_in[14];
    const float* fcW = (const float*)d_in[15];
    const float* fcb = (const float*)d_in[16];
    float* out = (float*)d_out;

    char* w = (char*)d_ws;
    auto alloc = [&](size_t bytes) {
        void* p = (void*)w;
        w += (bytes + 255) & ~(size_t)255;
        return p;
    };
    int* cnt_cursor = (int*)alloc((size_t)NN * 4);       // counts, then cursor
    int* row_ptr = (int*)alloc((size_t)(NN + 1) * 4);
    int* blkSum = (int*)alloc(512);
    int* blkOff = (int*)alloc(512);
    int* gcur = (int*)alloc((size_t)NBK * 4);
    int* col = (int*)alloc((size_t)(NE + NN) * 4);
    int* gs = (int*)alloc((size_t)(NG + 1) * 4);
    uint2* ebuf = (uint2*)alloc((size_t)NE * 8);
    __half* H = (__half*)alloc((size_t)NN * 64 * 2);
    float* Y = (float*)alloc((size_t)NN * 64 * 4);
    float* ssrc = (float*)alloc((size_t)NN * 4);
    float* sdst = (float*)alloc((size_t)NN * 4);

    const int* srcA = ei;
    const int* dstA = ei + NE;

    // CSR build: hist -> scan -> LDS counting-sort (A) -> windowed place (B)
    k_init_cnt<<<(NN + 255) / 256, 256, 0, stream>>>(cnt_cursor, NN);
    k_hist<<<(NE + 255) / 256, 256, 0, stream>>>(dstA, NE, cnt_cursor);
    const int nb = (NN + 1023) / 1024;  // 98
    k_scan1<<<nb, 1024, 0, stream>>>(cnt_cursor, NN, row_ptr, blkSum);
    k_scan2<<<1, 128, 0, stream>>>(blkSum, nb, blkOff, row_ptr + NN);
    k_scan3<<<(NN + 255) / 256, 256, 0, stream>>>(row_ptr, cnt_cursor, blkOff, NN);
    k_binit<<<(NBK + 255) / 256, 256, 0, stream>>>(row_ptr, gcur);
    k_sortA<<<(NE + SBATCH - 1) / SBATCH, 256, 0, stream>>>(srcA, dstA, NE, gcur, ebuf);
    k_sortB<<<(NE + NN + 255) / 256, 256, 0, stream>>>(ebuf, NE, NN, cnt_cursor, col);
    k_gstart<<<3, 256, 0, stream>>>(batch, NN, gs);

    const int gemm_grid = (NN + 63) / 64;   // 64-row tile per block
    const int agg_grid = (NN + 3) / 4;      // 4 waves per block, wave per dst

    // layer 0
    k_gemm_att<128><<<gemm_grid, 256, 0, stream>>>(x, W0, as0, ad0, H, ssrc, sdst, NN);
    k_agg4<<<agg_grid, 256, 0, stream>>>((const float2*)H, ssrc, sdst, row_ptr, col,
                                         (const float4*)b0, (float4*)Y, NN);
    // layer 1
    k_gemm_att<64><<<gemm_grid, 256, 0, stream>>>(Y, W1, as1, ad1, H, ssrc, sdst, NN);
    k_agg4<<<agg_grid, 256, 0, stream>>>((const float2*)H, ssrc, sdst, row_ptr, col,
                                         (const float4*)b1, (float4*)Y, NN);
    // layer 2
    k_gemm_att<64><<<gemm_grid, 256, 0, stream>>>(Y, W2, as2, ad2, H, ssrc, sdst, NN);
    k_agg4<<<agg_grid, 256, 0, stream>>>((const float2*)H, ssrc, sdst, row_ptr, col,
                                         (const float4*)b2, (float4*)Y, NN);

    // pool + FC
    k_pool_fc<<<NG, 64, 0, stream>>>(Y, gs, fcW, fcb, out);
}

// Round 7
// 366.826 us; speedup vs baseline: 1.9600x; 1.1626x over previous
//
#include <hip/hip_runtime.h>
#include <hip/hip_bf16.h>
#include <hip/hip_fp16.h>

#define NN 100000
#define NE 1200000
#define NG 512
#define NBK ((NN + 511) / 512)     // 196 dst buckets of 512 nodes
#define SBATCH 4096                 // edges per sort block
#define EPB (SBATCH / 256)          // edges per thread

// ---------------- CSR build ----------------
__global__ void k_init_cnt(int* cnt, int n) {
    int i = blockIdx.x * blockDim.x + threadIdx.x;
    if (i < n) cnt[i] = 1;  // self-loop contributes 1 per node
}

__global__ void k_hist(const int* __restrict__ dst, int e, int* cnt) {
    int i = blockIdx.x * blockDim.x + threadIdx.x;
    if (i < e) atomicAdd(&cnt[dst[i]], 1);
}

__global__ void k_scan1(const int* __restrict__ cnt, int n, int* ex, int* blkSum) {
    __shared__ int s[1024];
    int i = blockIdx.x * 1024 + threadIdx.x;
    int v = (i < n) ? cnt[i] : 0;
    s[threadIdx.x] = v;
    __syncthreads();
    for (int off = 1; off < 1024; off <<= 1) {
        int t = (threadIdx.x >= off) ? s[threadIdx.x - off] : 0;
        __syncthreads();
        s[threadIdx.x] += t;
        __syncthreads();
    }
    if (i < n) ex[i] = s[threadIdx.x] - v;   // exclusive within block
    if (threadIdx.x == 1023) blkSum[blockIdx.x] = s[1023];
}

__global__ void k_scan2(const int* __restrict__ blkSum, int nb, int* blkOff, int* totalOut) {
    __shared__ int s[128];
    int t = threadIdx.x;
    int v = (t < nb) ? blkSum[t] : 0;
    s[t] = v;
    __syncthreads();
    for (int off = 1; off < 128; off <<= 1) {
        int x = (t >= off) ? s[t - off] : 0;
        __syncthreads();
        s[t] += x;
        __syncthreads();
    }
    if (t < nb) blkOff[t] = s[t] - v;
    if (t == 127) *totalOut = s[127];  // row_ptr[N] = total edge count
}

__global__ void k_scan3(int* row_ptr, int* cursor, const int* __restrict__ blkOff, int n) {
    int i = blockIdx.x * blockDim.x + threadIdx.x;
    if (i < n) {
        int v = row_ptr[i] + blkOff[i >> 10];
        row_ptr[i] = v;
        cursor[i] = v;
    }
}

// bucket region start in ebuf: edges of dsts < b*512, excluding their self-loops
__global__ void k_binit(const int* __restrict__ row_ptr, int* gcur) {
    int b = blockIdx.x * blockDim.x + threadIdx.x;
    if (b < NBK) {
        int d0 = b * 512;
        if (d0 > NN) d0 = NN;
        gcur[b] = row_ptr[d0] - d0;
    }
}

// pass A: per-block LDS histogram + chunk reservation + dense record write
__global__ __launch_bounds__(256) void k_sortA(
    const int* __restrict__ srcA, const int* __restrict__ dstA, int e,
    int* gcur, uint2* __restrict__ ebuf) {
    __shared__ int cnt[NBK];
    __shared__ int base[NBK];
    const int t = threadIdx.x;
    const int i0 = blockIdx.x * SBATCH;
    for (int b = t; b < NBK; b += 256) cnt[b] = 0;
    __syncthreads();
#pragma unroll
    for (int k = 0; k < EPB; ++k) {
        int i = i0 + k * 256 + t;
        if (i < e) atomicAdd(&cnt[dstA[i] >> 9], 1);
    }
    __syncthreads();
    for (int b = t; b < NBK; b += 256) {
        int c = cnt[b];
        base[b] = c ? atomicAdd(&gcur[b], c) : 0;
        cnt[b] = 0;
    }
    __syncthreads();
#pragma unroll
    for (int k = 0; k < EPB; ++k) {
        int i = i0 + k * 256 + t;
        if (i < e) {
            int d = dstA[i], s = srcA[i];
            int b = d >> 9;
            int off = atomicAdd(&cnt[b], 1);
            ebuf[base[b] + off] = make_uint2((unsigned)s, (unsigned)d);
        }
    }
}

// pass B: bucket-grouped records -> col writes land in ~26KB windows
__global__ void k_sortB(const uint2* __restrict__ ebuf, int e, int n,
                        int* cursor, int* __restrict__ col) {
    int i = blockIdx.x * blockDim.x + threadIdx.x;
    if (i < e) {
        uint2 r = ebuf[i];
        int pos = atomicAdd(&cursor[(int)r.y], 1);
        col[pos] = (int)r.x;
    } else if (i < e + n) {
        int v = i - e;  // self loop
        int pos = atomicAdd(&cursor[v], 1);
        col[pos] = v;
    }
}

// ---------------- tiled GEMM + attention scores ----------------
// H(fp16) = X @ W  (X:[n,K] f32, W:[K,64]); ssrc = H.a_src, sdst = H.a_dst (f32).
template <int K>
__global__ __launch_bounds__(256) void k_gemm_att(
    const float* __restrict__ X, const float* __restrict__ W,
    const float* __restrict__ a_src, const float* __restrict__ a_dst,
    __half* __restrict__ H, float* __restrict__ ssrc, float* __restrict__ sdst, int n) {
    constexpr int KP = K + 8;              // padded X row stride (floats)
    __shared__ float Xs[64 * KP];
    __shared__ float Ws[K * 68];           // padded W row stride = 68
    const int tid = threadIdx.x;
    const int row0 = blockIdx.x * 64;

    for (int i = tid; i < K * 16; i += 256) {
        int k = i >> 4, c4 = i & 15;
        float4 v = reinterpret_cast<const float4*>(W)[i];
        *reinterpret_cast<float4*>(&Ws[k * 68 + c4 * 4]) = v;
    }
    constexpr int RQ = K / 4;              // float4s per row
    for (int i = tid; i < 64 * RQ; i += 256) {
        int r = i / RQ, c4 = i % RQ;
        float4 v = make_float4(0.f, 0.f, 0.f, 0.f);
        if (row0 + r < n) v = reinterpret_cast<const float4*>(X + (size_t)(row0 + r) * K)[c4];
        *reinterpret_cast<float4*>(&Xs[r * KP + c4 * 4]) = v;
    }
    __syncthreads();

    const int tx = tid & 15, ty = tid >> 4;   // 16x16 thread grid
    float acc[4][4] = {};
    for (int k = 0; k < K; k += 4) {
        float4 xv[4], wv[4];
#pragma unroll
        for (int r = 0; r < 4; ++r)
            xv[r] = *reinterpret_cast<const float4*>(&Xs[(ty * 4 + r) * KP + k]);
#pragma unroll
        for (int j = 0; j < 4; ++j)
            wv[j] = *reinterpret_cast<const float4*>(&Ws[(k + j) * 68 + tx * 4]);
#pragma unroll
        for (int r = 0; r < 4; ++r) {
            const float* xp = reinterpret_cast<const float*>(&xv[r]);
#pragma unroll
            for (int j = 0; j < 4; ++j) {
                const float* wp = reinterpret_cast<const float*>(&wv[j]);
#pragma unroll
                for (int c = 0; c < 4; ++c) acc[r][c] += xp[j] * wp[c];
            }
        }
    }

    float4 av = reinterpret_cast<const float4*>(a_src)[tx];
    float4 dv = reinterpret_cast<const float4*>(a_dst)[tx];
#pragma unroll
    for (int r = 0; r < 4; ++r) {
        int row = row0 + ty * 4 + r;
        if (row < n) {
            __half2 h01 = __floats2half2_rn(acc[r][0], acc[r][1]);
            __half2 h23 = __floats2half2_rn(acc[r][2], acc[r][3]);
            float2 packed;
            *reinterpret_cast<__half2*>(&packed.x) = h01;
            *reinterpret_cast<__half2*>(&packed.y) = h23;
            reinterpret_cast<float2*>(H + (size_t)row * 64)[tx] = packed;
            float ps = acc[r][0] * av.x + acc[r][1] * av.y + acc[r][2] * av.z + acc[r][3] * av.w;
            float pd = acc[r][0] * dv.x + acc[r][1] * dv.y + acc[r][2] * dv.z + acc[r][3] * dv.w;
#pragma unroll
            for (int off = 1; off < 16; off <<= 1) {
                ps += __shfl_xor(ps, off);
                pd += __shfl_xor(pd, off);
            }
            if (tx == 0) {
                ssrc[row] = ps;
                sdst[row] = pd;
            }
        }
    }
}

// ---------------- fused softmax + aggregation (wave per dst) ----------------
// phase 1: lane = edge slot (softmax). phase 2: 4 groups x 16 lanes; each
// group gathers one fp16 H row (16 x 8B) -> 4 rows per wave-issue.
__global__ __launch_bounds__(256) void k_agg4(
    const float2* __restrict__ H2, const float* __restrict__ ssrc,
    const float* __restrict__ sdst, const int* __restrict__ row_ptr,
    const int* __restrict__ col, const float4* __restrict__ bias4,
    float4* __restrict__ Y4, int n) {
    int dst = blockIdx.x * 4 + (threadIdx.x >> 6);
    int lane = threadIdx.x & 63;
    if (dst >= n) return;
    int beg = row_ptr[dst], end = row_ptr[dst + 1];
    int deg = end - beg;
    float sd = sdst[dst];
    const int grp = lane >> 4;   // edge group 0..3
    const int fl = lane & 15;    // 4-feature slot within row
    float4 acc = make_float4(0.f, 0.f, 0.f, 0.f);
    float den;

    auto fma_row = [&](int s, float w) {
        float2 raw = H2[(size_t)s * 16 + fl];
        const __half2* ph = reinterpret_cast<const __half2*>(&raw);
        float2 lo = __half22float2(ph[0]);
        float2 hi = __half22float2(ph[1]);
        acc.x += w * lo.x; acc.y += w * lo.y;
        acc.z += w * hi.x; acc.w += w * hi.y;
    };

    if (deg <= 64) {
        // phase 1: lane = edge slot
        int s_l = 0;
        float e = -INFINITY;
        if (lane < deg) {
            s_l = col[beg + lane];
            e = ssrc[s_l] + sd;
            e = (e > 0.f) ? e : 0.2f * e;
        }
        float m = e;
#pragma unroll
        for (int off = 32; off; off >>= 1) m = fmaxf(m, __shfl_xor(m, off));
        float w_l = (lane < deg) ? __expf(e - m) : 0.f;
        den = w_l;
#pragma unroll
        for (int off = 32; off; off >>= 1) den += __shfl_xor(den, off);

        // phase 2: 8 edges per iteration (2 per group)
        for (int jj = 0; jj < deg; jj += 8) {
            int j0 = jj + grp, j1 = jj + 4 + grp;
            int s0 = __shfl(s_l, j0), s1 = __shfl(s_l, j1);
            float w0 = __shfl(w_l, j0), w1 = __shfl(w_l, j1);
            if (j0 < deg) fma_row(s0, w0);
            if (j1 < deg) fma_row(s1, w1);
        }
    } else {
        // slow path: online softmax over chunks of 64, then grouped accumulate
        float m = -INFINITY, d2 = 0.f;
        for (int c = beg; c < end; c += 64) {
            int j = c + lane;
            float e = -INFINITY;
            if (j < end) {
                e = ssrc[col[j]] + sd;
                e = (e > 0.f) ? e : 0.2f * e;
            }
            float cm = e;
#pragma unroll
            for (int off = 32; off; off >>= 1) cm = fmaxf(cm, __shfl_xor(cm, off));
            float nm = fmaxf(m, cm);
            float term = (j < end) ? __expf(e - nm) : 0.f;
#pragma unroll
            for (int off = 32; off; off >>= 1) term += __shfl_xor(term, off);
            d2 = d2 * __expf(m - nm) + term;
            m = nm;
        }
        den = d2;
        for (int jj = 0; jj < deg; jj += 8) {
            int j0 = beg + jj + grp, j1 = beg + jj + 4 + grp;
            if (j0 < end) {
                int s = col[j0];
                float e = ssrc[s] + sd;
                e = (e > 0.f) ? e : 0.2f * e;
                fma_row(s, __expf(e - m));
            }
            if (j1 < end) {
                int s = col[j1];
                float e = ssrc[s] + sd;
                e = (e > 0.f) ? e : 0.2f * e;
                fma_row(s, __expf(e - m));
            }
        }
    }

    // cross-group reduce: sum the 4 edge-group partials (same fl)
#pragma unroll
    for (int off = 16; off < 64; off <<= 1) {
        acc.x += __shfl_xor(acc.x, off);
        acc.y += __shfl_xor(acc.y, off);
        acc.z += __shfl_xor(acc.z, off);
        acc.w += __shfl_xor(acc.w, off);
    }
    if (grp == 0) {
        float inv = 1.f / den;
        float4 b = bias4[fl];
        float4 o;
        o.x = fmaxf(acc.x * inv + b.x, 0.f);
        o.y = fmaxf(acc.y * inv + b.y, 0.f);
        o.z = fmaxf(acc.z * inv + b.z, 0.f);
        o.w = fmaxf(acc.w * inv + b.w, 0.f);
        Y4[(size_t)dst * 16 + fl] = o;
    }
}

// ---------------- pooling boundaries + pool + FC ----------------
__global__ void k_gstart(const int* __restrict__ batch, int n, int* gs) {
    int g = blockIdx.x * blockDim.x + threadIdx.x;
    if (g > NG) return;
    int lo = 0, hi = n;
    while (lo < hi) {
        int mid = (lo + hi) >> 1;
        if (batch[mid] < g) lo = mid + 1; else hi = mid;
    }
    gs[g] = lo;
}

// one graph per 256-thread block: 16 rows in flight (4 waves x 4 groups x
// float4 lanes), shfl+LDS reduce, then FC on wave 0.
__global__ __launch_bounds__(256) void k_pool_fc(
    const float4* __restrict__ Y4, const int* __restrict__ gs,
    const float* __restrict__ fcW, const float* __restrict__ fcb,
    float* __restrict__ out) {
    __shared__ float4 part[4][16];
    __shared__ float p[64];
    const int g = blockIdx.x, tid = threadIdx.x;
    const int wave = tid >> 6, lane = tid & 63;
    const int grp = lane >> 4, fl = lane & 15;
    const int b = gs[g], e = gs[g + 1];

    float4 acc = make_float4(0.f, 0.f, 0.f, 0.f);
    for (int r = b + wave * 4 + grp; r < e; r += 16) {
        float4 v = Y4[(size_t)r * 16 + fl];
        acc.x += v.x; acc.y += v.y; acc.z += v.z; acc.w += v.w;
    }
#pragma unroll
    for (int off = 16; off < 64; off <<= 1) {
        acc.x += __shfl_xor(acc.x, off);
        acc.y += __shfl_xor(acc.y, off);
        acc.z += __shfl_xor(acc.z, off);
        acc.w += __shfl_xor(acc.w, off);
    }
    if (grp == 0) part[wave][fl] = acc;
    __syncthreads();
    if (tid < 16) {
        float4 s0 = part[0][tid], s1 = part[1][tid], s2 = part[2][tid], s3 = part[3][tid];
        float inv = 1.f / (float)((e - b) > 0 ? (e - b) : 1);
        p[tid * 4 + 0] = (s0.x + s1.x + s2.x + s3.x) * inv;
        p[tid * 4 + 1] = (s0.y + s1.y + s2.y + s3.y) * inv;
        p[tid * 4 + 2] = (s0.z + s1.z + s2.z + s3.z) * inv;
        p[tid * 4 + 3] = (s0.w + s1.w + s2.w + s3.w) * inv;
    }
    __syncthreads();
    if (tid < 32) {
        float accO = fcb[tid];
#pragma unroll
        for (int k = 0; k < 64; ++k) accO += p[k] * fcW[k * 32 + tid];
        out[g * 32 + tid] = accO;
    }
}

// ---------------- launch ----------------
extern "C" void kernel_launch(void* const* d_in, const int* in_sizes, int n_in,
                              void* d_out, int out_size, void* d_ws, size_t ws_size,
                              hipStream_t stream) {
    const float* x = (const float*)d_in[0];
    const int* ei = (const int*)d_in[1];
    const int* batch = (const int*)d_in[2];
    const float* W0 = (const float*)d_in[3];
    const float* as0 = (const float*)d_in[4];
    const float* ad0 = (const float*)d_in[5];
    const float* b0 = (const float*)d_in[6];
    const float* W1 = (const float*)d_in[7];
    const float* as1 = (const float*)d_in[8];
    const float* ad1 = (const float*)d_in[9];
    const float* b1 = (const float*)d_in[10];
    const float* W2 = (const float*)d_in[11];
    const float* as2 = (const float*)d_in[12];
    const float* ad2 = (const float*)d_in[13];
    const float* b2 = (const float*)d_in[14];
    const float* fcW = (const float*)d_in[15];
    const float* fcb = (const float*)d_in[16];
    float* out = (float*)d_out;

    char* w = (char*)d_ws;
    auto alloc = [&](size_t bytes) {
        void* p = (void*)w;
        w += (bytes + 255) & ~(size_t)255;
        return p;
    };
    int* cnt_cursor = (int*)alloc((size_t)NN * 4);       // counts, then cursor
    int* row_ptr = (int*)alloc((size_t)(NN + 1) * 4);
    int* blkSum = (int*)alloc(512);
    int* blkOff = (int*)alloc(512);
    int* gcur = (int*)alloc((size_t)NBK * 4);
    int* col = (int*)alloc((size_t)(NE + NN) * 4);
    int* gs = (int*)alloc((size_t)(NG + 1) * 4);
    uint2* ebuf = (uint2*)alloc((size_t)NE * 8);
    __half* H = (__half*)alloc((size_t)NN * 64 * 2);
    float* Y = (float*)alloc((size_t)NN * 64 * 4);
    float* ssrc = (float*)alloc((size_t)NN * 4);
    float* sdst = (float*)alloc((size_t)NN * 4);

    const int* srcA = ei;
    const int* dstA = ei + NE;

    // CSR build: hist -> scan -> LDS counting-sort (A) -> windowed place (B)
    k_init_cnt<<<(NN + 255) / 256, 256, 0, stream>>>(cnt_cursor, NN);
    k_hist<<<(NE + 255) / 256, 256, 0, stream>>>(dstA, NE, cnt_cursor);
    const int nb = (NN + 1023) / 1024;  // 98
    k_scan1<<<nb, 1024, 0, stream>>>(cnt_cursor, NN, row_ptr, blkSum);
    k_scan2<<<1, 128, 0, stream>>>(blkSum, nb, blkOff, row_ptr + NN);
    k_scan3<<<(NN + 255) / 256, 256, 0, stream>>>(row_ptr, cnt_cursor, blkOff, NN);
    k_binit<<<(NBK + 255) / 256, 256, 0, stream>>>(row_ptr, gcur);
    k_sortA<<<(NE + SBATCH - 1) / SBATCH, 256, 0, stream>>>(srcA, dstA, NE, gcur, ebuf);
    k_sortB<<<(NE + NN + 255) / 256, 256, 0, stream>>>(ebuf, NE, NN, cnt_cursor, col);
    k_gstart<<<3, 256, 0, stream>>>(batch, NN, gs);

    const int gemm_grid = (NN + 63) / 64;   // 64-row tile per block
    const int agg_grid = (NN + 3) / 4;      // 4 waves per block, wave per dst

    // layer 0
    k_gemm_att<128><<<gemm_grid, 256, 0, stream>>>(x, W0, as0, ad0, H, ssrc, sdst, NN);
    k_agg4<<<agg_grid, 256, 0, stream>>>((const float2*)H, ssrc, sdst, row_ptr, col,
                                         (const float4*)b0, (float4*)Y, NN);
    // layer 1
    k_gemm_att<64><<<gemm_grid, 256, 0, stream>>>(Y, W1, as1, ad1, H, ssrc, sdst, NN);
    k_agg4<<<agg_grid, 256, 0, stream>>>((const float2*)H, ssrc, sdst, row_ptr, col,
                                         (const float4*)b1, (float4*)Y, NN);
    // layer 2
    k_gemm_att<64><<<gemm_grid, 256, 0, stream>>>(Y, W2, as2, ad2, H, ssrc, sdst, NN);
    k_agg4<<<agg_grid, 256, 0, stream>>>((const float2*)H, ssrc, sdst, row_ptr, col,
                                         (const float4*)b2, (float4*)Y, NN);

    // pool + FC
    k_pool_fc<<<NG, 256, 0, stream>>>((const float4*)Y, gs, fcW, fcb, out);
}

// Round 8
// 335.719 us; speedup vs baseline: 2.1417x; 1.0927x over previous
//
#include <hip/hip_runtime.h>
#include <hip/hip_bf16.h>
#include <hip/hip_fp16.h>

#define NN 100000
#define NE 1200000
#define NG 512
#define NBK ((NN + 511) / 512)     // 196 dst buckets of 512 nodes
#define SBATCH 4096                 // edges per sort block
#define EPB (SBATCH / 256)          // edges per thread

// ---------------- CSR build ----------------
__global__ void k_init_cnt(int* cnt, int n) {
    int i = blockIdx.x * blockDim.x + threadIdx.x;
    if (i < n) cnt[i] = 1;  // self-loop contributes 1 per node
}

__global__ void k_hist(const int* __restrict__ dst, int e, int* cnt) {
    int i = blockIdx.x * blockDim.x + threadIdx.x;
    if (i < e) atomicAdd(&cnt[dst[i]], 1);
}

__global__ void k_scan1(const int* __restrict__ cnt, int n, int* ex, int* blkSum) {
    __shared__ int s[1024];
    int i = blockIdx.x * 1024 + threadIdx.x;
    int v = (i < n) ? cnt[i] : 0;
    s[threadIdx.x] = v;
    __syncthreads();
    for (int off = 1; off < 1024; off <<= 1) {
        int t = (threadIdx.x >= off) ? s[threadIdx.x - off] : 0;
        __syncthreads();
        s[threadIdx.x] += t;
        __syncthreads();
    }
    if (i < n) ex[i] = s[threadIdx.x] - v;   // exclusive within block
    if (threadIdx.x == 1023) blkSum[blockIdx.x] = s[1023];
}

__global__ void k_scan2(const int* __restrict__ blkSum, int nb, int* blkOff, int* totalOut) {
    __shared__ int s[128];
    int t = threadIdx.x;
    int v = (t < nb) ? blkSum[t] : 0;
    s[t] = v;
    __syncthreads();
    for (int off = 1; off < 128; off <<= 1) {
        int x = (t >= off) ? s[t - off] : 0;
        __syncthreads();
        s[t] += x;
        __syncthreads();
    }
    if (t < nb) blkOff[t] = s[t] - v;
    if (t == 127) *totalOut = s[127];  // row_ptr[N] = total edge count
}

__global__ void k_scan3(int* row_ptr, int* cursor, const int* __restrict__ blkOff, int n) {
    int i = blockIdx.x * blockDim.x + threadIdx.x;
    if (i < n) {
        int v = row_ptr[i] + blkOff[i >> 10];
        row_ptr[i] = v;
        cursor[i] = v;
    }
}

// bucket region start in ebuf: edges of dsts < b*512, excluding their self-loops
__global__ void k_binit(const int* __restrict__ row_ptr, int* gcur) {
    int b = blockIdx.x * blockDim.x + threadIdx.x;
    if (b < NBK) {
        int d0 = b * 512;
        if (d0 > NN) d0 = NN;
        gcur[b] = row_ptr[d0] - d0;
    }
}

// pass A: per-block LDS histogram + chunk reservation + dense record write
__global__ __launch_bounds__(256) void k_sortA(
    const int* __restrict__ srcA, const int* __restrict__ dstA, int e,
    int* gcur, uint2* __restrict__ ebuf) {
    __shared__ int cnt[NBK];
    __shared__ int base[NBK];
    const int t = threadIdx.x;
    const int i0 = blockIdx.x * SBATCH;
    for (int b = t; b < NBK; b += 256) cnt[b] = 0;
    __syncthreads();
#pragma unroll
    for (int k = 0; k < EPB; ++k) {
        int i = i0 + k * 256 + t;
        if (i < e) atomicAdd(&cnt[dstA[i] >> 9], 1);
    }
    __syncthreads();
    for (int b = t; b < NBK; b += 256) {
        int c = cnt[b];
        base[b] = c ? atomicAdd(&gcur[b], c) : 0;
        cnt[b] = 0;
    }
    __syncthreads();
#pragma unroll
    for (int k = 0; k < EPB; ++k) {
        int i = i0 + k * 256 + t;
        if (i < e) {
            int d = dstA[i], s = srcA[i];
            int b = d >> 9;
            int off = atomicAdd(&cnt[b], 1);
            ebuf[base[b] + off] = make_uint2((unsigned)s, (unsigned)d);
        }
    }
}

// pass B: bucket-grouped records -> col writes land in ~26KB windows
__global__ void k_sortB(const uint2* __restrict__ ebuf, int e, int n,
                        int* cursor, int* __restrict__ col) {
    int i = blockIdx.x * blockDim.x + threadIdx.x;
    if (i < e) {
        uint2 r = ebuf[i];
        int pos = atomicAdd(&cursor[(int)r.y], 1);
        col[pos] = (int)r.x;
    } else if (i < e + n) {
        int v = i - e;  // self loop
        int pos = atomicAdd(&cursor[v], 1);
        col[pos] = v;
    }
}

// ---------------- tiled GEMM + attention scores ----------------
// H(fp16) = X @ W ; X is f32 (layer 0) or fp16 (layers 1,2, converted in staging)
template <int K, bool HIN>
__global__ __launch_bounds__(256) void k_gemm_att(
    const float* __restrict__ Xf, const __half* __restrict__ Xh,
    const float* __restrict__ W,
    const float* __restrict__ a_src, const float* __restrict__ a_dst,
    __half* __restrict__ H, float* __restrict__ ssrc, float* __restrict__ sdst, int n) {
    constexpr int KP = K + 8;              // padded X row stride (floats)
    __shared__ float Xs[64 * KP];
    __shared__ float Ws[K * 68];           // padded W row stride = 68
    const int tid = threadIdx.x;
    const int row0 = blockIdx.x * 64;

    for (int i = tid; i < K * 16; i += 256) {
        int k = i >> 4, c4 = i & 15;
        float4 v = reinterpret_cast<const float4*>(W)[i];
        *reinterpret_cast<float4*>(&Ws[k * 68 + c4 * 4]) = v;
    }
    constexpr int RQ = K / 4;              // 4-float chunks per row
    for (int i = tid; i < 64 * RQ; i += 256) {
        int r = i / RQ, c4 = i % RQ;
        float4 v = make_float4(0.f, 0.f, 0.f, 0.f);
        if (row0 + r < n) {
            if constexpr (HIN) {
                float2 raw = reinterpret_cast<const float2*>(Xh + (size_t)(row0 + r) * K)[c4];
                const __half2* ph = reinterpret_cast<const __half2*>(&raw);
                float2 lo = __half22float2(ph[0]);
                float2 hi = __half22float2(ph[1]);
                v = make_float4(lo.x, lo.y, hi.x, hi.y);
            } else {
                v = reinterpret_cast<const float4*>(Xf + (size_t)(row0 + r) * K)[c4];
            }
        }
        *reinterpret_cast<float4*>(&Xs[r * KP + c4 * 4]) = v;
    }
    __syncthreads();

    const int tx = tid & 15, ty = tid >> 4;   // 16x16 thread grid
    float acc[4][4] = {};
    for (int k = 0; k < K; k += 4) {
        float4 xv[4], wv[4];
#pragma unroll
        for (int r = 0; r < 4; ++r)
            xv[r] = *reinterpret_cast<const float4*>(&Xs[(ty * 4 + r) * KP + k]);
#pragma unroll
        for (int j = 0; j < 4; ++j)
            wv[j] = *reinterpret_cast<const float4*>(&Ws[(k + j) * 68 + tx * 4]);
#pragma unroll
        for (int r = 0; r < 4; ++r) {
            const float* xp = reinterpret_cast<const float*>(&xv[r]);
#pragma unroll
            for (int j = 0; j < 4; ++j) {
                const float* wp = reinterpret_cast<const float*>(&wv[j]);
#pragma unroll
                for (int c = 0; c < 4; ++c) acc[r][c] += xp[j] * wp[c];
            }
        }
    }

    float4 av = reinterpret_cast<const float4*>(a_src)[tx];
    float4 dv = reinterpret_cast<const float4*>(a_dst)[tx];
#pragma unroll
    for (int r = 0; r < 4; ++r) {
        int row = row0 + ty * 4 + r;
        if (row < n) {
            __half2 h01 = __floats2half2_rn(acc[r][0], acc[r][1]);
            __half2 h23 = __floats2half2_rn(acc[r][2], acc[r][3]);
            float2 packed;
            *reinterpret_cast<__half2*>(&packed.x) = h01;
            *reinterpret_cast<__half2*>(&packed.y) = h23;
            reinterpret_cast<float2*>(H + (size_t)row * 64)[tx] = packed;
            float ps = acc[r][0] * av.x + acc[r][1] * av.y + acc[r][2] * av.z + acc[r][3] * av.w;
            float pd = acc[r][0] * dv.x + acc[r][1] * dv.y + acc[r][2] * dv.z + acc[r][3] * dv.w;
#pragma unroll
            for (int off = 1; off < 16; off <<= 1) {
                ps += __shfl_xor(ps, off);
                pd += __shfl_xor(pd, off);
            }
            if (tx == 0) {
                ssrc[row] = ps;
                sdst[row] = pd;
            }
        }
    }
}

// ---------------- fused softmax + aggregation (2 dsts per wave) ----------------
// Each 32-lane half owns one dst: 5-step softmax reductions, then 2 groups x
// 16 lanes gather fp16 H rows (2-deep unroll) -> 8 rows in flight per wave.
__global__ __launch_bounds__(256) void k_agg5(
    const float2* __restrict__ H2, const float* __restrict__ ssrc,
    const float* __restrict__ sdst, const int* __restrict__ row_ptr,
    const int* __restrict__ col, const float4* __restrict__ bias4,
    float2* __restrict__ Yh2, int n) {
    const int wave = threadIdx.x >> 6, lane = threadIdx.x & 63;
    const int hf = lane >> 5, hl = lane & 31;
    const int base = blockIdx.x * 8 + wave * 2;
    const int dst = base + hf;

    int beg = 0, end = 0;
    if (dst < n) { beg = row_ptr[dst]; end = row_ptr[dst + 1]; }
    int deg = end - beg;
    int dmax = max(deg, __shfl_xor(deg, 32));

    if (dmax <= 32) {
        float sd = (dst < n) ? sdst[dst] : 0.f;
        // phase 1: 32-lane softmax, lane = edge slot
        int s_l = 0;
        float e = -INFINITY;
        if (hl < deg) {
            s_l = col[beg + hl];
            e = ssrc[s_l] + sd;
            e = (e > 0.f) ? e : 0.2f * e;
        }
        float m = e;
#pragma unroll
        for (int off = 16; off; off >>= 1) m = fmaxf(m, __shfl_xor(m, off));
        float w_l = (hl < deg) ? __expf(e - m) : 0.f;
        float den = w_l;
#pragma unroll
        for (int off = 16; off; off >>= 1) den += __shfl_xor(den, off);

        // phase 2: 2 groups x 16 lanes, 2-deep unroll
        const int grp = hl >> 4, fl = hl & 15;
        float4 acc = make_float4(0.f, 0.f, 0.f, 0.f);
        for (int jj = 0; jj < deg; jj += 4) {
            int j0 = jj + grp, j1 = jj + 2 + grp;
            int s0 = __shfl(s_l, hf * 32 + j0), s1 = __shfl(s_l, hf * 32 + j1);
            float w0 = __shfl(w_l, hf * 32 + j0), w1 = __shfl(w_l, hf * 32 + j1);
            if (j0 < deg) {
                float2 raw = H2[(size_t)s0 * 16 + fl];
                const __half2* ph = reinterpret_cast<const __half2*>(&raw);
                float2 lo = __half22float2(ph[0]), hi = __half22float2(ph[1]);
                acc.x += w0 * lo.x; acc.y += w0 * lo.y;
                acc.z += w0 * hi.x; acc.w += w0 * hi.y;
            }
            if (j1 < deg) {
                float2 raw = H2[(size_t)s1 * 16 + fl];
                const __half2* ph = reinterpret_cast<const __half2*>(&raw);
                float2 lo = __half22float2(ph[0]), hi = __half22float2(ph[1]);
                acc.x += w1 * lo.x; acc.y += w1 * lo.y;
                acc.z += w1 * hi.x; acc.w += w1 * hi.y;
            }
        }
        // sum the 2 groups (xor 16 stays within the half)
        acc.x += __shfl_xor(acc.x, 16);
        acc.y += __shfl_xor(acc.y, 16);
        acc.z += __shfl_xor(acc.z, 16);
        acc.w += __shfl_xor(acc.w, 16);
        if (grp == 0 && dst < n) {
            float inv = 1.f / den;
            float4 b = bias4[fl];
            float ox = fmaxf(acc.x * inv + b.x, 0.f);
            float oy = fmaxf(acc.y * inv + b.y, 0.f);
            float oz = fmaxf(acc.z * inv + b.z, 0.f);
            float ow = fmaxf(acc.w * inv + b.w, 0.f);
            float2 packed;
            *reinterpret_cast<__half2*>(&packed.x) = __floats2half2_rn(ox, oy);
            *reinterpret_cast<__half2*>(&packed.y) = __floats2half2_rn(oz, ow);
            Yh2[(size_t)dst * 16 + fl] = packed;
        }
    } else {
        // slow path (rare): whole wave per dst, sequential over the 2 dsts
        for (int h = 0; h < 2; ++h) {
            int d = base + h;
            if (d >= n) break;
            int bg = row_ptr[d], en = row_ptr[d + 1];
            float sdd = sdst[d];
            float m = -INFINITY, d2 = 0.f;
            for (int c = bg; c < en; c += 64) {
                int j = c + lane;
                float e = -INFINITY;
                if (j < en) {
                    e = ssrc[col[j]] + sdd;
                    e = (e > 0.f) ? e : 0.2f * e;
                }
                float cm = e;
#pragma unroll
                for (int off = 32; off; off >>= 1) cm = fmaxf(cm, __shfl_xor(cm, off));
                float nm = fmaxf(m, cm);
                float term = (j < en) ? __expf(e - nm) : 0.f;
#pragma unroll
                for (int off = 32; off; off >>= 1) term += __shfl_xor(term, off);
                d2 = d2 * __expf(m - nm) + term;
                m = nm;
            }
            const int g4 = lane >> 4, fl = lane & 15;
            float4 acc = make_float4(0.f, 0.f, 0.f, 0.f);
            for (int jj = 0; jj < en - bg; jj += 8) {
                int j0 = bg + jj + g4, j1 = bg + jj + 4 + g4;
                if (j0 < en) {
                    int s = col[j0];
                    float e = ssrc[s] + sdd;
                    e = (e > 0.f) ? e : 0.2f * e;
                    float w = __expf(e - m);
                    float2 raw = H2[(size_t)s * 16 + fl];
                    const __half2* ph = reinterpret_cast<const __half2*>(&raw);
                    float2 lo = __half22float2(ph[0]), hi = __half22float2(ph[1]);
                    acc.x += w * lo.x; acc.y += w * lo.y;
                    acc.z += w * hi.x; acc.w += w * hi.y;
                }
                if (j1 < en) {
                    int s = col[j1];
                    float e = ssrc[s] + sdd;
                    e = (e > 0.f) ? e : 0.2f * e;
                    float w = __expf(e - m);
                    float2 raw = H2[(size_t)s * 16 + fl];
                    const __half2* ph = reinterpret_cast<const __half2*>(&raw);
                    float2 lo = __half22float2(ph[0]), hi = __half22float2(ph[1]);
                    acc.x += w * lo.x; acc.y += w * lo.y;
                    acc.z += w * hi.x; acc.w += w * hi.y;
                }
            }
#pragma unroll
            for (int off = 16; off < 64; off <<= 1) {
                acc.x += __shfl_xor(acc.x, off);
                acc.y += __shfl_xor(acc.y, off);
                acc.z += __shfl_xor(acc.z, off);
                acc.w += __shfl_xor(acc.w, off);
            }
            if (g4 == 0) {
                float inv = 1.f / d2;
                float4 b = bias4[fl];
                float ox = fmaxf(acc.x * inv + b.x, 0.f);
                float oy = fmaxf(acc.y * inv + b.y, 0.f);
                float oz = fmaxf(acc.z * inv + b.z, 0.f);
                float ow = fmaxf(acc.w * inv + b.w, 0.f);
                float2 packed;
                *reinterpret_cast<__half2*>(&packed.x) = __floats2half2_rn(ox, oy);
                *reinterpret_cast<__half2*>(&packed.y) = __floats2half2_rn(oz, ow);
                Yh2[(size_t)d * 16 + fl] = packed;
            }
        }
    }
}

// ---------------- pooling boundaries + pool + FC ----------------
__global__ void k_gstart(const int* __restrict__ batch, int n, int* gs) {
    int g = blockIdx.x * blockDim.x + threadIdx.x;
    if (g > NG) return;
    int lo = 0, hi = n;
    while (lo < hi) {
        int mid = (lo + hi) >> 1;
        if (batch[mid] < g) lo = mid + 1; else hi = mid;
    }
    gs[g] = lo;
}

// one graph per 256-thread block: 16 fp16 rows in flight, shfl+LDS reduce, FC.
__global__ __launch_bounds__(256) void k_pool_fc(
    const float2* __restrict__ Yh2, const int* __restrict__ gs,
    const float* __restrict__ fcW, const float* __restrict__ fcb,
    float* __restrict__ out) {
    __shared__ float4 part[4][16];
    __shared__ float p[64];
    const int g = blockIdx.x, tid = threadIdx.x;
    const int wave = tid >> 6, lane = tid & 63;
    const int grp = lane >> 4, fl = lane & 15;
    const int b = gs[g], e = gs[g + 1];

    float4 acc = make_float4(0.f, 0.f, 0.f, 0.f);
    for (int r = b + wave * 4 + grp; r < e; r += 16) {
        float2 raw = Yh2[(size_t)r * 16 + fl];
        const __half2* ph = reinterpret_cast<const __half2*>(&raw);
        float2 lo = __half22float2(ph[0]), hi = __half22float2(ph[1]);
        acc.x += lo.x; acc.y += lo.y; acc.z += hi.x; acc.w += hi.y;
    }
#pragma unroll
    for (int off = 16; off < 64; off <<= 1) {
        acc.x += __shfl_xor(acc.x, off);
        acc.y += __shfl_xor(acc.y, off);
        acc.z += __shfl_xor(acc.z, off);
        acc.w += __shfl_xor(acc.w, off);
    }
    if (grp == 0) part[wave][fl] = acc;
    __syncthreads();
    if (tid < 16) {
        float4 s0 = part[0][tid], s1 = part[1][tid], s2 = part[2][tid], s3 = part[3][tid];
        float inv = 1.f / (float)((e - b) > 0 ? (e - b) : 1);
        p[tid * 4 + 0] = (s0.x + s1.x + s2.x + s3.x) * inv;
        p[tid * 4 + 1] = (s0.y + s1.y + s2.y + s3.y) * inv;
        p[tid * 4 + 2] = (s0.z + s1.z + s2.z + s3.z) * inv;
        p[tid * 4 + 3] = (s0.w + s1.w + s2.w + s3.w) * inv;
    }
    __syncthreads();
    if (tid < 32) {
        float accO = fcb[tid];
#pragma unroll
        for (int k = 0; k < 64; ++k) accO += p[k] * fcW[k * 32 + tid];
        out[g * 32 + tid] = accO;
    }
}

// ---------------- launch ----------------
extern "C" void kernel_launch(void* const* d_in, const int* in_sizes, int n_in,
                              void* d_out, int out_size, void* d_ws, size_t ws_size,
                              hipStream_t stream) {
    const float* x = (const float*)d_in[0];
    const int* ei = (const int*)d_in[1];
    const int* batch = (const int*)d_in[2];
    const float* W0 = (const float*)d_in[3];
    const float* as0 = (const float*)d_in[4];
    const float* ad0 = (const float*)d_in[5];
    const float* b0 = (const float*)d_in[6];
    const float* W1 = (const float*)d_in[7];
    const float* as1 = (const float*)d_in[8];
    const float* ad1 = (const float*)d_in[9];
    const float* b1 = (const float*)d_in[10];
    const float* W2 = (const float*)d_in[11];
    const float* as2 = (const float*)d_in[12];
    const float* ad2 = (const float*)d_in[13];
    const float* b2 = (const float*)d_in[14];
    const float* fcW = (const float*)d_in[15];
    const float* fcb = (const float*)d_in[16];
    float* out = (float*)d_out;

    char* w = (char*)d_ws;
    auto alloc = [&](size_t bytes) {
        void* p = (void*)w;
        w += (bytes + 255) & ~(size_t)255;
        return p;
    };
    int* cnt_cursor = (int*)alloc((size_t)NN * 4);       // counts, then cursor
    int* row_ptr = (int*)alloc((size_t)(NN + 1) * 4);
    int* blkSum = (int*)alloc(512);
    int* blkOff = (int*)alloc(512);
    int* gcur = (int*)alloc((size_t)NBK * 4);
    int* col = (int*)alloc((size_t)(NE + NN) * 4);
    int* gs = (int*)alloc((size_t)(NG + 1) * 4);
    uint2* ebuf = (uint2*)alloc((size_t)NE * 8);
    __half* H = (__half*)alloc((size_t)NN * 64 * 2);
    __half* Y = (__half*)alloc((size_t)NN * 64 * 2);
    float* ssrc = (float*)alloc((size_t)NN * 4);
    float* sdst = (float*)alloc((size_t)NN * 4);

    const int* srcA = ei;
    const int* dstA = ei + NE;

    // CSR build: hist -> scan -> LDS counting-sort (A) -> windowed place (B)
    k_init_cnt<<<(NN + 255) / 256, 256, 0, stream>>>(cnt_cursor, NN);
    k_hist<<<(NE + 255) / 256, 256, 0, stream>>>(dstA, NE, cnt_cursor);
    const int nb = (NN + 1023) / 1024;  // 98
    k_scan1<<<nb, 1024, 0, stream>>>(cnt_cursor, NN, row_ptr, blkSum);
    k_scan2<<<1, 128, 0, stream>>>(blkSum, nb, blkOff, row_ptr + NN);
    k_scan3<<<(NN + 255) / 256, 256, 0, stream>>>(row_ptr, cnt_cursor, blkOff, NN);
    k_binit<<<(NBK + 255) / 256, 256, 0, stream>>>(row_ptr, gcur);
    k_sortA<<<(NE + SBATCH - 1) / SBATCH, 256, 0, stream>>>(srcA, dstA, NE, gcur, ebuf);
    k_sortB<<<(NE + NN + 255) / 256, 256, 0, stream>>>(ebuf, NE, NN, cnt_cursor, col);
    k_gstart<<<3, 256, 0, stream>>>(batch, NN, gs);

    const int gemm_grid = (NN + 63) / 64;   // 64-row tile per block
    const int agg_grid = (NN + 7) / 8;      // 4 waves x 2 dsts per block

    // layer 0 (f32 input)
    k_gemm_att<128, false><<<gemm_grid, 256, 0, stream>>>(x, nullptr, W0, as0, ad0,
                                                          H, ssrc, sdst, NN);
    k_agg5<<<agg_grid, 256, 0, stream>>>((const float2*)H, ssrc, sdst, row_ptr, col,
                                         (const float4*)b0, (float2*)Y, NN);
    // layer 1 (fp16 input)
    k_gemm_att<64, true><<<gemm_grid, 256, 0, stream>>>(nullptr, Y, W1, as1, ad1,
                                                        H, ssrc, sdst, NN);
    k_agg5<<<agg_grid, 256, 0, stream>>>((const float2*)H, ssrc, sdst, row_ptr, col,
                                         (const float4*)b1, (float2*)Y, NN);
    // layer 2 (fp16 input)
    k_gemm_att<64, true><<<gemm_grid, 256, 0, stream>>>(nullptr, Y, W2, as2, ad2,
                                                        H, ssrc, sdst, NN);
    k_agg5<<<agg_grid, 256, 0, stream>>>((const float2*)H, ssrc, sdst, row_ptr, col,
                                         (const float4*)b2, (float2*)Y, NN);

    // pool + FC
    k_pool_fc<<<NG, 256, 0, stream>>>((const float2*)Y, gs, fcW, fcb, out);
}